// Round 5
// baseline (727.531 us; speedup 1.0000x reference)
//
#include <hip/hip_runtime.h>
#include <hip/hip_bf16.h>

// SNN + STDP fused simulation, round 5 (R4 + compile fix: sv1 -> sv0).
// (1) lgkmcnt-only barriers (vmem prefetch stays in flight across s_barrier),
// (2) uniform-post fast path: when all post_tr[b] are bitwise equal and spike
// masks are all-ones/all-zero (pre-spike + saturated regimes, ~55% of steps),
// dep/pot collapse to dW = CP*(full?S[i]:0) - CM*post_c*colcnt[i] with zero
// LDS gathers; detected exactly at runtime by an idle wave,
// (3) row-list entries pre-scaled to byte offsets, (4) fused mask pre-pass.

#define TT    350
#define BB    128
#define INF   784
#define NNEU  400
#define NS    2
#define NTHR  1024
#define LCAP  80           // row-list capacity (u16 entries, pad = INF<<3)

#define ALPHA 0.9f
#define BETA  0.8f
#define BPLUS 0.9f
#define BMIN  0.9f
#define CP    (0.008f/128.0f)
#define CM    (0.0008f/128.0f)

__device__ __forceinline__ float bf2f(__hip_bfloat16 v){ return __bfloat162float(v); }

// lgkmcnt-only barrier: do NOT drain vmcnt (prefetches span barriers).
__device__ __forceinline__ void barx(){
  asm volatile("s_waitcnt lgkmcnt(0)" ::: "memory");
  __builtin_amdgcn_s_barrier();
  __builtin_amdgcn_sched_barrier(0);
}

// ---- pre-pass 1: pre_tr timeline (fp32 recurrence, stored bf16) ----
__global__ void k_pretr(const float* __restrict__ img, __hip_bfloat16* __restrict__ pre){
  int idx = blockIdx.x*blockDim.x + threadIdx.x;      // (b,i) flat
  if (idx >= BB*INF) return;
  float v = 0.f;
  for (int t=0;t<TT;t++){
    v = BPLUS*v + img[(size_t)t*(BB*INF) + idx];
    pre[(size_t)t*(BB*INF) + idx] = __float2bfloat16(v);
  }
}

// ---- pre-pass 2: S[t,i] = sum_b pre_bf16[t,b,i] (fp32 accum) ----
__global__ void k_S(const __hip_bfloat16* __restrict__ pre, float* __restrict__ S){
  int idx = blockIdx.x*blockDim.x + threadIdx.x;      // t*INF + i
  if (idx >= TT*INF) return;
  int t = idx / INF, i = idx - t*INF;
  const __hip_bfloat16* p = pre + (size_t)t*(BB*INF) + i;
  float s = 0.f;
  for (int b=0;b<BB;b++) s += bf2f(p[(size_t)b*INF]);
  S[idx] = s;
}

// ---- pre-pass 3 (fused): row bit-stage -> row lists + column byte-lists ----
__global__ void k_masks(const float* __restrict__ img,
                        unsigned short* __restrict__ lists,
                        int* __restrict__ cnts,
                        unsigned int* __restrict__ collist){
  __shared__ unsigned long long rowbits[BB][13];      // 13.3 KB
  __shared__ unsigned short buf[16][LCAP];            // 2.5 KB
  const int t = blockIdx.x;
  const int tid = threadIdx.x, lane = tid & 63, w = tid >> 6;
  const float* base = img + (size_t)t*(BB*INF);

  // stage bits: wave w owns rows 8w..8w+7
  for (int r8=0; r8<8; r8++){
    int r = w*8 + r8;
    const float* p = base + (size_t)r*INF;
    for (int c=0;c<13;c++){
      int i = c*64 + lane;
      bool a = (i < INF) && (p[i] > 0.f);
      unsigned long long bal = __ballot(a);
      if (lane == 0) rowbits[r][c] = bal;
    }
  }
  // row lists (prefix-compact per row), entries pre-scaled by 8
  for (int r8=0; r8<8; r8++){
    int r = w*8 + r8;
    int cnt = 0;
    for (int c=0;c<13;c++){
      unsigned long long word = rowbits[r][c];        // broadcast read
      int i = c*64 + lane;
      bool a = (word >> lane) & 1ull;
      int pos = cnt + __popcll(word & ((1ull<<lane)-1ull));
      if (a && pos < LCAP) buf[w][pos] = (unsigned short)(i<<3);
      cnt += __popcll(word);
    }
    for (int k = cnt + lane; k < LCAP; k += 64) buf[w][k] = (unsigned short)(INF<<3);
    if (lane == 0) cnts[t*BB + r] = (cnt < LCAP) ? cnt : LCAP;
    if (lane < LCAP/2)
      ((unsigned int*)(lists + (size_t)(t*BB + r)*LCAP))[lane] = ((unsigned int*)buf[w])[lane];
  }
  __syncthreads();
  // column byte-lists: 32B per (t,i): [cnt, entries..., pad=128]
  if (tid < INF){
    int wsel = tid >> 6, bit = tid & 63;
    unsigned long long m0=0, m1=0;
    for (int b=0;b<64;b++) m0 |= ((rowbits[b][wsel]    >> bit) & 1ull) << b;
    for (int b=0;b<64;b++) m1 |= ((rowbits[64+b][wsel] >> bit) & 1ull) << b;
    int cnt = __popcll(m0) + __popcll(m1);
    unsigned int wd[8];
    wd[0] = (unsigned int)cnt; wd[1]=0;wd[2]=0;wd[3]=0;wd[4]=0;wd[5]=0;wd[6]=0;wd[7]=0;
    #pragma unroll
    for (int k=1;k<32;k++){
      int bb;
      if (m0){ bb = __builtin_ctzll(m0); m0 &= m0-1; }
      else if (m1){ bb = 64 + __builtin_ctzll(m1); m1 &= m1-1; }
      else bb = 128;
      wd[k>>2] |= ((unsigned int)bb) << ((k&3)*8);
    }
    uint4* dst = (uint4*)(collist + ((size_t)t*INF + tid)*8);
    uint4 lo; lo.x=wd[0]; lo.y=wd[1]; lo.z=wd[2]; lo.w=wd[3];
    uint4 hi; hi.x=wd[4]; hi.y=wd[5]; hi.z=wd[6]; hi.w=wd[7];
    dst[0]=lo; dst[1]=hi;
  }
}

__device__ __forceinline__ float potf(unsigned long long ma, unsigned long long mb,
                                      int pc, float Sv,
                                      const __hip_bfloat16* __restrict__ prt, int c){
  bool direct = (pc <= 64);
  unsigned long long m = direct ? ma : ~ma;
  unsigned long long n = direct ? mb : ~mb;
  float acc = 0.f;
  while (m){ int bb = __builtin_ctzll(m); m &= m-1; acc += bf2f(prt[(size_t)bb*INF + c]); }
  while (n){ int bb = __builtin_ctzll(n); n &= n-1; acc += bf2f(prt[(size_t)(64+bb)*INF + c]); }
  return direct ? acc : (Sv - acc);
}

#define G2(W) { float2 a_ = *(const float2*)((const char*)&Wp2[0] + ((W) & 0xffffu)); I0 += a_.x; I1 += a_.y; \
                float2 b_ = *(const float2*)((const char*)&Wp2[0] + ((W) >> 16));     I0 += b_.x; I1 += b_.y; }
#define GATHER8(V) { G2((V).x); G2((V).y); G2((V).z); G2((V).w); }

#define DEP4(W) { float2 p_; \
  p_ = postl[(W) & 0xffu];        d0 += p_.x; d1 += p_.y; \
  p_ = postl[((W)>>8) & 0xffu];   d0 += p_.x; d1 += p_.y; \
  p_ = postl[((W)>>16) & 0xffu];  d0 += p_.x; d1 += p_.y; \
  p_ = postl[(W)>>24];            d0 += p_.x; d1 += p_.y; }

#define DOCOL(c, cl, sv) { \
  float d0=0.f, d1=0.f; \
  unsigned int w0_ = (cl).x; \
  { float2 p_; \
    p_ = postl[(w0_>>8) & 0xffu];  d0 += p_.x; d1 += p_.y; \
    p_ = postl[(w0_>>16) & 0xffu]; d0 += p_.x; d1 += p_.y; \
    p_ = postl[w0_>>24];           d0 += p_.x; d1 += p_.y; } \
  DEP4((cl).y); DEP4((cl).z); DEP4((cl).w); \
  int cc_ = (int)(w0_ & 0xffu); \
  if (cc_ > 15){ \
    uint4 e2_ = *(const uint4*)(collist + ((size_t)t*INF + (c))*8 + 4); \
    DEP4(e2_.x); DEP4(e2_.y); DEP4(e2_.z); DEP4(e2_.w); \
  } \
  float pot0_ = potf(s00, s01, pc0, (sv), prt, (c)); \
  float pot1_ = potf(s10, s11, pc1, (sv), prt, (c)); \
  float2 wv_ = Wp2[(c)]; \
  wv_.x = fminf(fmaxf(wv_.x + CP*pot0_ - CM*d0, 0.f), 1.f); \
  wv_.y = fminf(fmaxf(wv_.y + CP*pot1_ - CM*d1, 0.f), 1.f); \
  Wp2[(c)] = wv_; }

__launch_bounds__(NTHR, 1)
__global__ void k_main(const float* __restrict__ Win,
                       const __hip_bfloat16* __restrict__ pre,
                       const float* __restrict__ S,
                       const unsigned short* __restrict__ lists,
                       const int* __restrict__ cnts,
                       const unsigned int* __restrict__ collist,
                       float* __restrict__ out){
  __shared__ float2 Wp2[800];                  // [i] -> (W[n0][i], W[n0+1][i]); 784.. = 0 pad
  __shared__ float2 postl[132];                // [b] -> (post0, post1); 128.. = 0 pad
  __shared__ unsigned long long smQ[2][2];     // spike masks per neuron
  __shared__ float cntS[2];
  __shared__ float2 postCb[2];                 // uniform post value (parity dbuf)
  __shared__ int    unifb[2];                  // postl-all-equal flag (parity dbuf)

  const int tid  = threadIdx.x;
  const int lane = tid & 63;
  const int wv   = tid >> 6;                   // wave 0..15
  const int q    = lane >> 3;                  // 8-way I split
  const int b    = (wv << 3) | (lane & 7);     // batch 0..127
  const int n0   = blockIdx.x * NS;

  if (tid < 800){
    float2 w;
    w.x = (tid < INF) ? Win[(size_t)n0*INF + tid] : 0.f;
    w.y = (tid < INF) ? Win[(size_t)(n0+1)*INF + tid] : 0.f;
    Wp2[tid] = w;
  }
  if (tid < 132){ postl[tid].x = 0.f; postl[tid].y = 0.f; }
  if (tid < 2) cntS[tid] = 0.f;
  if (tid == 0){
    postCb[0].x = 0.f; postCb[0].y = 0.f; unifb[0] = 1;
    postCb[1].x = 0.f; postCb[1].y = 0.f; unifb[1] = 1;
  }

  const int  c0   = tid;
  const bool hasc = (c0 < INF);

  float syn0=0.f, mem0=0.f, syn1=0.f, mem1=0.f, sc0=0.f, sc1=0.f;

  // t=0 prefetch
  uint4 lA = *(const uint4*)(lists + ((size_t)b)*LCAP + (size_t)q*8);
  int cn = cnts[b];
  uint4 cl0; cl0.x=0;cl0.y=0;cl0.z=0;cl0.w=0;
  float sv0 = 0.f;
  if (hasc){ cl0 = *(const uint4*)(collist + (size_t)c0*8); sv0 = S[c0]; }

  __syncthreads();

  for (int t=0; t<TT; t++){
    // ---- I partial gather: 8 list entries, both neurons per ds_read_b64 ----
    float I0 = 0.f, I1 = 0.f;
    GATHER8(lA);
    if (cn > 64 + q*8){                         // entries 64..79 (q=0,1), rare
      uint4 lC = *(const uint4*)(lists + ((size_t)t*BB + b)*LCAP + 64 + (size_t)q*8);
      GATHER8(lC);
    }
    // ---- prefetch t+1 (in flight across barriers; never drained) ----
    int tn = (t+1 < TT) ? t+1 : TT-1;
    uint4 lAn = *(const uint4*)(lists + ((size_t)tn*BB + b)*LCAP + (size_t)q*8);
    int cnn = cnts[tn*BB + b];
    uint4 cl0n = cl0; float sv0n = sv0;
    if (hasc){
      cl0n = *(const uint4*)(collist + ((size_t)tn*INF + c0)*8);
      sv0n = S[tn*INF + c0];
    }

    // ---- combine 8 partials in-wave ----
    I0 += __shfl_xor(I0, 8); I0 += __shfl_xor(I0, 16); I0 += __shfl_xor(I0, 32);
    I1 += __shfl_xor(I1, 8); I1 += __shfl_xor(I1, 16); I1 += __shfl_xor(I1, 32);

    // ---- LIF (redundant across q, identical fp ops) ----
    float r0 = (mem0 > 1.f) ? 1.f : 0.f;
    syn0 = ALPHA*syn0 + I0;
    mem0 = BETA*mem0 + syn0 - r0;
    float s0 = (mem0 > 1.f) ? 1.f : 0.f;
    float r1 = (mem1 > 1.f) ? 1.f : 0.f;
    syn1 = ALPHA*syn1 + I1;
    mem1 = BETA*mem1 + syn1 - r1;
    float s1 = (mem1 > 1.f) ? 1.f : 0.f;
    unsigned long long bal0 = __ballot(s0 > 0.5f);
    unsigned long long bal1 = __ballot(s1 > 0.5f);
    if (q == 0){
      sc0 += s0; sc1 += s1;
      float2 pv = postl[b];
      pv.x = BMIN*pv.x + s0;
      pv.y = BMIN*pv.y + s1;
      postl[b] = pv;
    }
    if (lane == 0){
      ((unsigned char*)smQ)[wv]      = (unsigned char)(bal0 & 0xffu);
      ((unsigned char*)smQ)[16 + wv] = (unsigned char)(bal1 & 0xffu);
    }
    barx();                                     // postl + smQ visible

    // ---- dW + W update; thread owns column c0 ----
    unsigned long long s00 = smQ[0][0], s01 = smQ[0][1];
    unsigned long long s10 = smQ[1][0], s11 = smQ[1][1];
    bool full0 = (s00 & s01) == ~0ull, none0 = (s00 | s01) == 0ull;
    bool full1 = (s10 & s11) == ~0ull, none1 = (s10 | s11) == 0ull;
    int   fastOK = unifb[t & 1] && (full0 || none0) && (full1 || none1);
    float2 pC = postCb[t & 1];

    // wave13 (idle in column phase): value-check post uniformity for t+1
    if (wv == 13){
      float2 a0 = postl[lane], a1 = postl[64 + lane];
      float2 rr = postl[0];
      bool eq = (a0.x==rr.x) && (a0.y==rr.y) && (a1.x==rr.x) && (a1.y==rr.y);
      unsigned long long bal = __ballot(eq);
      if (lane == 0){ unifb[(t+1) & 1] = (bal == ~0ull); postCb[(t+1) & 1] = rr; }
    }

    if (fastOK){
      if (hasc){
        float sa0 = full0 ? 1.f : 0.f, sa1 = full1 ? 1.f : 0.f;
        float cur0 = BMIN*pC.x + sa0, cur1 = BMIN*pC.y + sa1;
        bool allzero = none0 && none1 && (pC.x == 0.f) && (pC.y == 0.f);
        if (!allzero){
          float cc  = (float)(int)(cl0.x & 0xffu);
          float pot0 = full0 ? sv0 : 0.f;
          float pot1 = full1 ? sv0 : 0.f;
          float2 wv_ = Wp2[c0];
          wv_.x = fminf(fmaxf(wv_.x + CP*pot0 - CM*(cur0*cc), 0.f), 1.f);
          wv_.y = fminf(fmaxf(wv_.y + CP*pot1 - CM*(cur1*cc), 0.f), 1.f);
          Wp2[c0] = wv_;
        }
      }
    } else {
      int pc0 = __popcll(s00) + __popcll(s01);
      int pc1 = __popcll(s10) + __popcll(s11);
      const __hip_bfloat16* prt = pre + (size_t)t*(BB*INF);
      if (hasc) DOCOL(c0, cl0, sv0)
    }

    lA=lAn; cn=cnn; cl0=cl0n; sv0=sv0n;
    barx();                                     // Wp2 updates visible for next I
  }

  __syncthreads();
  // ---- outputs: [W (400x784)] [mem (128x400)] [syn (128x400)] [counts (400)] ----
  if (tid < INF){
    float2 wvv = Wp2[tid];
    out[(size_t)n0*INF + tid]       = wvv.x;
    out[(size_t)(n0+1)*INF + tid]   = wvv.y;
  }
  if (q == 0){
    out[(size_t)NNEU*INF + (size_t)b*NNEU + n0]                        = mem0;
    out[(size_t)NNEU*INF + (size_t)b*NNEU + n0 + 1]                    = mem1;
    out[(size_t)NNEU*INF + (size_t)BB*NNEU + (size_t)b*NNEU + n0]      = syn0;
    out[(size_t)NNEU*INF + (size_t)BB*NNEU + (size_t)b*NNEU + n0 + 1]  = syn1;
    atomicAdd(&cntS[0], sc0);
    atomicAdd(&cntS[1], sc1);
  }
  __syncthreads();
  if (tid < 2) out[(size_t)NNEU*INF + 2*(size_t)BB*NNEU + n0 + tid] = cntS[tid];
}

extern "C" void kernel_launch(void* const* d_in, const int* in_sizes, int n_in,
                              void* d_out, int out_size, void* d_ws, size_t ws_size,
                              hipStream_t stream) {
  const float* img = (const float*)d_in[0];   // [T,B,IN] float32 (0/1)
  const float* W   = (const float*)d_in[1];   // [N,IN] float32
  float* out = (float*)d_out;

  // workspace carve (total 87,472,000 B)
  char* ws = (char*)d_ws;
  __hip_bfloat16* pre  = (__hip_bfloat16*)ws;                  // 70,246,400
  float*          S    = (float*)(ws + 70246400);              //  1,097,600
  unsigned short* lst  = (unsigned short*)(ws + 71344000);     //  7,168,000
  int*            cnts = (int*)(ws + 78512000);                //    179,200
  unsigned int*   coll = (unsigned int*)(ws + 78691200);       //  8,780,800

  k_pretr<<<(BB*INF + 255)/256, 256, 0, stream>>>(img, pre);
  k_masks<<<TT, NTHR, 0, stream>>>(img, lst, cnts, coll);
  k_S    <<<(TT*INF + 255)/256, 256, 0, stream>>>(pre, S);
  k_main <<<NNEU/NS, NTHR, 0, stream>>>(W, pre, S, lst, cnts, coll, out);
}